// Round 5
// baseline (1905.770 us; speedup 1.0000x reference)
//
#include <hip/hip_runtime.h>
#include <math.h>

constexpr int SCAN_TPB = 256;
constexpr int SCAN_EPT = 8;                      // elements per thread
constexpr int SCAN_EPB = SCAN_TPB * SCAN_EPT;    // 2048 per block

// ---------------- degree (in-degree over dst) ----------------
__global__ void k_deg(const int* __restrict__ dst, int* __restrict__ deg, int E) {
    int i = blockIdx.x * blockDim.x + threadIdx.x;
    if (i < E) atomicAdd(&deg[dst[i]], 1);
}

// ---------------- scan phase A: per-block sums ----------------
__global__ __launch_bounds__(SCAN_TPB) void k_blocksum(const int* __restrict__ deg,
                                                       int* __restrict__ bsum, int n) {
    int t = threadIdx.x;
    int idx0 = blockIdx.x * SCAN_EPB + t * SCAN_EPT;
    int s = 0;
    if (idx0 + SCAN_EPT <= n) {
        const int4* p = reinterpret_cast<const int4*>(deg + idx0);
        int4 a = p[0], b = p[1];
        s = a.x + a.y + a.z + a.w + b.x + b.y + b.z + b.w;
    } else {
        for (int k = 0; k < SCAN_EPT; ++k) { int i = idx0 + k; if (i < n) s += deg[i]; }
    }
#pragma unroll
    for (int off = 32; off; off >>= 1) s += __shfl_xor(s, off);
    __shared__ int wsum[4];
    int lane = t & 63, wid = t >> 6;
    if (lane == 0) wsum[wid] = s;
    __syncthreads();
    if (t == 0) bsum[blockIdx.x] = wsum[0] + wsum[1] + wsum[2] + wsum[3];
}

// ---------------- scan phase B: exclusive-scan the block sums (tiny) ----------------
__global__ __launch_bounds__(256) void k_scanbsum(int* __restrict__ bsum,
                                                  int* __restrict__ row_off, int nb, int n) {
    int t = threadIdx.x, lane = t & 63, wid = t >> 6;
    __shared__ int wsum[4];
    int carry = 0;
    for (int base = 0; base < nb; base += 256) {
        int i = base + t;
        int v = (i < nb) ? bsum[i] : 0;
        int s = v;
#pragma unroll
        for (int off = 1; off < 64; off <<= 1) { int u = __shfl_up(s, off); if (lane >= off) s += u; }
        if (lane == 63) wsum[wid] = s;
        __syncthreads();
        int add = carry;
        for (int w = 0; w < wid; ++w) add += wsum[w];
        if (i < nb) bsum[i] = s - v + add;        // exclusive + carry
        carry += wsum[0] + wsum[1] + wsum[2] + wsum[3];
        __syncthreads();
    }
    if (t == 0) row_off[n] = carry;               // total edge count
}

// ---------------- scan phase C: final scan, write row_off + cursor ----------------
__global__ __launch_bounds__(SCAN_TPB) void k_scanfinal(const int* __restrict__ deg,
                                                        const int* __restrict__ bsum,
                                                        int* __restrict__ row_off,
                                                        int* __restrict__ cursor, int n) {
    int t = threadIdx.x, lane = t & 63, wid = t >> 6;
    int idx0 = blockIdx.x * SCAN_EPB + t * SCAN_EPT;
    int e[SCAN_EPT];
    bool full = (idx0 + SCAN_EPT <= n);
    if (full) {
        const int4* p = reinterpret_cast<const int4*>(deg + idx0);
        int4 a = p[0], b = p[1];
        e[0] = a.x; e[1] = a.y; e[2] = a.z; e[3] = a.w;
        e[4] = b.x; e[5] = b.y; e[6] = b.z; e[7] = b.w;
    } else {
        for (int k = 0; k < SCAN_EPT; ++k) { int i = idx0 + k; e[k] = (i < n) ? deg[i] : 0; }
    }
    int tsum = 0;
#pragma unroll
    for (int k = 0; k < SCAN_EPT; ++k) tsum += e[k];
    int s = tsum;
#pragma unroll
    for (int off = 1; off < 64; off <<= 1) { int u = __shfl_up(s, off); if (lane >= off) s += u; }
    __shared__ int wsum[4];
    if (lane == 63) wsum[wid] = s;
    __syncthreads();
    int add = bsum[blockIdx.x];
    for (int w = 0; w < wid; ++w) add += wsum[w];
    int run = s - tsum + add;                     // thread's exclusive prefix
    int o[SCAN_EPT];
#pragma unroll
    for (int k = 0; k < SCAN_EPT; ++k) { o[k] = run; run += e[k]; }
    if (full) {
        int4* ro = reinterpret_cast<int4*>(row_off + idx0);
        int4* cu = reinterpret_cast<int4*>(cursor + idx0);
        ro[0] = make_int4(o[0], o[1], o[2], o[3]);
        ro[1] = make_int4(o[4], o[5], o[6], o[7]);
        cu[0] = make_int4(o[0], o[1], o[2], o[3]);
        cu[1] = make_int4(o[4], o[5], o[6], o[7]);
    } else {
        for (int k = 0; k < SCAN_EPT; ++k) {
            int i = idx0 + k;
            if (i < n) { row_off[i] = o[k]; cursor[i] = o[k]; }
        }
    }
}

// ---------------- dinv + pre-scaled features xsc[i] = x[i]*dinv[i] ----------------
__global__ void k_dinvx(const int* __restrict__ deg, const float* __restrict__ x,
                        float* __restrict__ dinv, float2* __restrict__ xsc, int n) {
    int i = blockIdx.x * blockDim.x + threadIdx.x;
    if (i < n) {
        float di = rsqrtf((float)deg[i] + 1.0f);  // +1 self loop, always > 0
        dinv[i] = di;
        xsc[i] = make_float2(x[2 * i] * di, x[2 * i + 1] * di);
    }
}

// ---------------- CSR fill (counting sort by dst) ----------------
__global__ void k_fill(const int* __restrict__ src, const int* __restrict__ dst,
                       int* __restrict__ cursor, int* __restrict__ csr_src, int E) {
    int e = blockIdx.x * blockDim.x + threadIdx.x;
    if (e < E) {
        int pos = atomicAdd(&cursor[dst[e]], 1);
        csr_src[pos] = src[e];
    }
}

// ---------------- layer-1 sparse aggregation: xam[i] = dinv[i]*(xsc[i] + sum_nbr xsc[s])
// thread per node (avg deg 3; csr ranges consecutive across threads -> ~coalesced)
__global__ __launch_bounds__(256) void k_agg1(
    const float2* __restrict__ xsc, const float* __restrict__ dinv,
    const int* __restrict__ row_off, const int* __restrict__ csr_src,
    float2* __restrict__ xam, int n) {
    int i = blockIdx.x * blockDim.x + threadIdx.x;
    if (i >= n) return;
    int r0 = row_off[i], r1 = row_off[i + 1];
    float2 self = xsc[i];
    float xa0 = self.x, xa1 = self.y;
    for (int j = r0; j < r1; ++j) {
        float2 v = xsc[csr_src[j]];               // 8B gather, xsc=1.6MB L2-resident
        xa0 += v.x; xa1 += v.y;
    }
    float di = dinv[i];
    xam[i] = make_float2(xa0 * di, xa1 * di);
}

// ---------------- layer-1 dense part: h1 = relu(xam@W1+b1); m2 = (h1@W2)*dinv
// Tiled: 32 nodes/block, W2^T staged in LDS (reused by all 32 nodes -> no global
// re-reads; round-4 lesson: per-node W2 reads = 6.4GB L2 traffic). Wave: lane =
// out-feature, 8 nodes in acc registers; h1 reads are wave-uniform broadcasts.
constexpr int GN  = 32;    // nodes per block
constexpr int GM  = 8;     // nodes per wave
constexpr int LDH = 132;   // padded LDS row stride (16B-aligned, even bank spread)

__global__ __launch_bounds__(256) void k_gemm1(
    const float2* __restrict__ xam, const float* __restrict__ dinv,
    const float* __restrict__ W1, const float* __restrict__ b1,
    const float* __restrict__ W2, float* __restrict__ m2, int n) {
    __shared__ __align__(16) float W2t[64 * LDH];   // [f][k] transposed
    __shared__ __align__(16) float h1s[GN * LDH];   // [m][k]
    int t = threadIdx.x;
    int wid = t >> 6, lane = t & 63;
    int base = blockIdx.x * GN;

    // stage W2 (row-major [128][64]) transposed into LDS
    for (int idx = t; idx < 128 * 64; idx += 256) {
        int k = idx >> 6, f = idx & 63;
        W2t[f * LDH + k] = W2[idx];
    }
    // h1 tile: thread -> node m = t>>3, k-range (t&7)*16..+16
    {
        int m = t >> 3, g = t & 7;
        int i = base + m;
        float2 xa = (i < n) ? xam[i] : make_float2(0.f, 0.f);
#pragma unroll
        for (int k = g * 16; k < g * 16 + 16; k += 4) {
            float4 wa = *reinterpret_cast<const float4*>(&W1[k]);        // W1[0][k..]
            float4 wb = *reinterpret_cast<const float4*>(&W1[128 + k]);  // W1[1][k..]
            float4 bb = *reinterpret_cast<const float4*>(&b1[k]);
            float4 h;
            h.x = fmaxf(fmaf(xa.y, wb.x, fmaf(xa.x, wa.x, bb.x)), 0.f);
            h.y = fmaxf(fmaf(xa.y, wb.y, fmaf(xa.x, wa.y, bb.y)), 0.f);
            h.z = fmaxf(fmaf(xa.y, wb.z, fmaf(xa.x, wa.z, bb.z)), 0.f);
            h.w = fmaxf(fmaf(xa.y, wb.w, fmaf(xa.x, wa.w, bb.w)), 0.f);
            *reinterpret_cast<float4*>(&h1s[m * LDH + k]) = h;
        }
    }
    __syncthreads();

    float acc[GM];
#pragma unroll
    for (int m = 0; m < GM; ++m) acc[m] = 0.f;
    int mbase = wid * GM;
#pragma unroll
    for (int k4 = 0; k4 < 32; ++k4) {
        float4 w = *reinterpret_cast<const float4*>(&W2t[lane * LDH + 4 * k4]);
#pragma unroll
        for (int m = 0; m < GM; ++m) {            // broadcast reads + 8 indep FMA chains
            float4 h = *reinterpret_cast<const float4*>(&h1s[(mbase + m) * LDH + 4 * k4]);
            acc[m] = fmaf(h.x, w.x, acc[m]);
            acc[m] = fmaf(h.y, w.y, acc[m]);
            acc[m] = fmaf(h.z, w.z, acc[m]);
            acc[m] = fmaf(h.w, w.w, acc[m]);
        }
    }
#pragma unroll
    for (int m = 0; m < GM; ++m) {
        int i = base + mbase + m;
        if (i < n) m2[(size_t)i * 64 + lane] = acc[m] * dinv[i];  // pre-scaled by dinv[src]
    }
}

// ---------------- layer 2 gather + full epilogue, one wave per node ----------------
__global__ __launch_bounds__(256) void k_l2out(
    const float* __restrict__ m2, const float* __restrict__ dinv,
    const int* __restrict__ row_off, const int* __restrict__ csr_src,
    const float* __restrict__ b2, const float* __restrict__ Wp,
    const float* __restrict__ bp, float* __restrict__ out, int n) {
    int tid = threadIdx.x;
    int wid = tid >> 6, lane = tid & 63;
    float b2l = b2[lane], wpl = Wp[lane], bp0 = bp[0];
    int i = blockIdx.x * 4 + wid;
    if (i >= n) return;
    int r0 = row_off[i], r1 = row_off[i + 1];
    float acc = m2[(size_t)i * 64 + lane];          // self-loop term
    for (int j = r0; j < r1; ++j) {
        int s = csr_src[j];
        acc += m2[(size_t)s * 64 + lane];           // coalesced 256B row gather (L3-resident)
    }
    float v = fmaxf(acc * dinv[i] + b2l, 0.f) * wpl;
#pragma unroll
    for (int off = 32; off; off >>= 1) v += __shfl_xor(v, off);
    if (lane == 0) out[i] = 1.f / (1.f + expf(-(v + bp0)));
}

extern "C" void kernel_launch(void* const* d_in, const int* in_sizes, int n_in,
                              void* d_out, int out_size, void* d_ws, size_t ws_size,
                              hipStream_t stream) {
    const float* x  = (const float*)d_in[0];
    const int*   ei = (const int*)d_in[1];   // [2, E] int32
    const float* W1 = (const float*)d_in[2];
    const float* b1 = (const float*)d_in[3];
    const float* W2 = (const float*)d_in[4];
    const float* b2 = (const float*)d_in[5];
    const float* Wp = (const float*)d_in[6];
    const float* bp = (const float*)d_in[7];
    float* out = (float*)d_out;

    int n = in_sizes[0] / 2;
    int E = in_sizes[1] / 2;
    const int* src = ei;
    const int* dst = ei + E;

    char* ws = (char*)d_ws;
    size_t off = 0;
    auto alloc = [&](size_t bytes) -> void* {
        void* p = ws + off;
        off += (bytes + 255) & ~(size_t)255;
        return p;
    };
    int nb = (n + SCAN_EPB - 1) / SCAN_EPB;
    int*    deg     = (int*)alloc((size_t)n * 4);
    int*    bsum    = (int*)alloc((size_t)nb * 4);
    int*    row_off = (int*)alloc((size_t)(n + 1) * 4);
    int*    cursor  = (int*)alloc((size_t)n * 4);
    float*  dinv    = (float*)alloc((size_t)n * 4);
    float2* xsc     = (float2*)alloc((size_t)n * 8);
    float2* xam     = (float2*)alloc((size_t)n * 8);
    int*    csr_src = (int*)alloc((size_t)E * 4);
    float*  m2      = (float*)alloc((size_t)n * 64 * 4);
    (void)ws_size;

    hipMemsetAsync(deg, 0, (size_t)n * 4, stream);
    k_deg      <<<(E + 255) / 256, 256, 0, stream>>>(dst, deg, E);
    k_blocksum <<<nb, SCAN_TPB, 0, stream>>>(deg, bsum, n);
    k_scanbsum <<<1, 256, 0, stream>>>(bsum, row_off, nb, n);
    k_scanfinal<<<nb, SCAN_TPB, 0, stream>>>(deg, bsum, row_off, cursor, n);
    k_dinvx    <<<(n + 255) / 256, 256, 0, stream>>>(deg, x, dinv, xsc, n);
    k_fill     <<<(E + 255) / 256, 256, 0, stream>>>(src, dst, cursor, csr_src, E);
    k_agg1     <<<(n + 255) / 256, 256, 0, stream>>>(xsc, dinv, row_off, csr_src, xam, n);
    k_gemm1    <<<(n + GN - 1) / GN, 256, 0, stream>>>(xam, dinv, W1, b1, W2, m2, n);
    k_l2out    <<<(n + 3) / 4, 256, 0, stream>>>(m2, dinv, row_off, csr_src, b2, Wp, bp, out, n);
}

// Round 6
// 251.069 us; speedup vs baseline: 7.5906x; 7.5906x over previous
//
#include <hip/hip_runtime.h>
#include <math.h>

constexpr int SCAN_TPB = 256;
constexpr int SCAN_EPT = 8;                      // elements per thread
constexpr int SCAN_EPB = SCAN_TPB * SCAN_EPT;    // 2048 per block

// ---------------- degree (in-degree over dst) ----------------
__global__ void k_deg(const int* __restrict__ dst, int* __restrict__ deg, int E) {
    int i = blockIdx.x * blockDim.x + threadIdx.x;
    if (i < E) atomicAdd(&deg[dst[i]], 1);
}

// ---------------- scan phase A: per-block sums ----------------
__global__ __launch_bounds__(SCAN_TPB) void k_blocksum(const int* __restrict__ deg,
                                                       int* __restrict__ bsum, int n) {
    int t = threadIdx.x;
    int idx0 = blockIdx.x * SCAN_EPB + t * SCAN_EPT;
    int s = 0;
    if (idx0 + SCAN_EPT <= n) {
        const int4* p = reinterpret_cast<const int4*>(deg + idx0);
        int4 a = p[0], b = p[1];
        s = a.x + a.y + a.z + a.w + b.x + b.y + b.z + b.w;
    } else {
        for (int k = 0; k < SCAN_EPT; ++k) { int i = idx0 + k; if (i < n) s += deg[i]; }
    }
#pragma unroll
    for (int off = 32; off; off >>= 1) s += __shfl_xor(s, off);
    __shared__ int wsum[4];
    int lane = t & 63, wid = t >> 6;
    if (lane == 0) wsum[wid] = s;
    __syncthreads();
    if (t == 0) bsum[blockIdx.x] = wsum[0] + wsum[1] + wsum[2] + wsum[3];
}

// ---------------- scan phase B: exclusive-scan the block sums (tiny) ----------------
__global__ __launch_bounds__(256) void k_scanbsum(int* __restrict__ bsum,
                                                  int* __restrict__ row_off, int nb, int n) {
    int t = threadIdx.x, lane = t & 63, wid = t >> 6;
    __shared__ int wsum[4];
    int carry = 0;
    for (int base = 0; base < nb; base += 256) {
        int i = base + t;
        int v = (i < nb) ? bsum[i] : 0;
        int s = v;
#pragma unroll
        for (int off = 1; off < 64; off <<= 1) { int u = __shfl_up(s, off); if (lane >= off) s += u; }
        if (lane == 63) wsum[wid] = s;
        __syncthreads();
        int add = carry;
        for (int w = 0; w < wid; ++w) add += wsum[w];
        if (i < nb) bsum[i] = s - v + add;        // exclusive + carry
        carry += wsum[0] + wsum[1] + wsum[2] + wsum[3];
        __syncthreads();
    }
    if (t == 0) row_off[n] = carry;               // total edge count
}

// ---------------- scan phase C: final scan, write row_off + cursor ----------------
__global__ __launch_bounds__(SCAN_TPB) void k_scanfinal(const int* __restrict__ deg,
                                                        const int* __restrict__ bsum,
                                                        int* __restrict__ row_off,
                                                        int* __restrict__ cursor, int n) {
    int t = threadIdx.x, lane = t & 63, wid = t >> 6;
    int idx0 = blockIdx.x * SCAN_EPB + t * SCAN_EPT;
    int e[SCAN_EPT];
    bool full = (idx0 + SCAN_EPT <= n);
    if (full) {
        const int4* p = reinterpret_cast<const int4*>(deg + idx0);
        int4 a = p[0], b = p[1];
        e[0] = a.x; e[1] = a.y; e[2] = a.z; e[3] = a.w;
        e[4] = b.x; e[5] = b.y; e[6] = b.z; e[7] = b.w;
    } else {
        for (int k = 0; k < SCAN_EPT; ++k) { int i = idx0 + k; e[k] = (i < n) ? deg[i] : 0; }
    }
    int tsum = 0;
#pragma unroll
    for (int k = 0; k < SCAN_EPT; ++k) tsum += e[k];
    int s = tsum;
#pragma unroll
    for (int off = 1; off < 64; off <<= 1) { int u = __shfl_up(s, off); if (lane >= off) s += u; }
    __shared__ int wsum[4];
    if (lane == 63) wsum[wid] = s;
    __syncthreads();
    int add = bsum[blockIdx.x];
    for (int w = 0; w < wid; ++w) add += wsum[w];
    int run = s - tsum + add;                     // thread's exclusive prefix
    int o[SCAN_EPT];
#pragma unroll
    for (int k = 0; k < SCAN_EPT; ++k) { o[k] = run; run += e[k]; }
    if (full) {
        int4* ro = reinterpret_cast<int4*>(row_off + idx0);
        int4* cu = reinterpret_cast<int4*>(cursor + idx0);
        ro[0] = make_int4(o[0], o[1], o[2], o[3]);
        ro[1] = make_int4(o[4], o[5], o[6], o[7]);
        cu[0] = make_int4(o[0], o[1], o[2], o[3]);
        cu[1] = make_int4(o[4], o[5], o[6], o[7]);
    } else {
        for (int k = 0; k < SCAN_EPT; ++k) {
            int i = idx0 + k;
            if (i < n) { row_off[i] = o[k]; cursor[i] = o[k]; }
        }
    }
}

// ---------------- dinv + pre-scaled features xsc[i] = x[i]*dinv[i] ----------------
__global__ void k_dinvx(const int* __restrict__ deg, const float* __restrict__ x,
                        float* __restrict__ dinv, float2* __restrict__ xsc, int n) {
    int i = blockIdx.x * blockDim.x + threadIdx.x;
    if (i < n) {
        float di = rsqrtf((float)deg[i] + 1.0f);  // +1 self loop, always > 0
        dinv[i] = di;
        xsc[i] = make_float2(x[2 * i] * di, x[2 * i + 1] * di);
    }
}

// ---------------- CSR fill (counting sort by dst) ----------------
__global__ void k_fill(const int* __restrict__ src, const int* __restrict__ dst,
                       int* __restrict__ cursor, int* __restrict__ csr_src, int E) {
    int e = blockIdx.x * blockDim.x + threadIdx.x;
    if (e < E) {
        int pos = atomicAdd(&cursor[dst[e]], 1);
        csr_src[pos] = src[e];
    }
}

// ---------------- layer-1 sparse aggregation: xam[i] = dinv[i]*(xsc[i] + sum_nbr xsc[s])
__global__ __launch_bounds__(256) void k_agg1(
    const float2* __restrict__ xsc, const float* __restrict__ dinv,
    const int* __restrict__ row_off, const int* __restrict__ csr_src,
    float2* __restrict__ xam, int n) {
    int i = blockIdx.x * blockDim.x + threadIdx.x;
    if (i >= n) return;
    int r0 = row_off[i], r1 = row_off[i + 1];
    float2 self = xsc[i];
    float xa0 = self.x, xa1 = self.y;
    for (int j = r0; j < r1; ++j) {
        float2 v = xsc[csr_src[j]];               // 8B gather, xsc=1.6MB L2-resident
        xa0 += v.x; xa1 += v.y;
    }
    float di = dinv[i];
    xam[i] = make_float2(xa0 * di, xa1 * di);
}

// ---------------- layer-1 dense part: h1 = relu(xam@W1+b1); m2 = (h1@W2)*dinv
// Round-5 lesson: FULL unroll of the k-loop over float4 LDS reads exploded the
// live set (VGPR=256 + 6 GB scratch spill traffic). Keep unroll=2 and cap regs
// via __launch_bounds__(256,2): live set ~60 VGPR, no spills.
constexpr int GN  = 32;    // nodes per block
constexpr int GM  = 8;     // nodes per wave
constexpr int LDH = 132;   // padded LDS row stride (16B-aligned)

__global__ __launch_bounds__(256, 2) void k_gemm1(
    const float2* __restrict__ xam, const float* __restrict__ dinv,
    const float* __restrict__ W1, const float* __restrict__ b1,
    const float* __restrict__ W2, float* __restrict__ m2, int n) {
    __shared__ __align__(16) float W2t[64 * LDH];   // [f][k] transposed, 33.8 KB
    __shared__ __align__(16) float h1s[GN * LDH];   // [m][k], 16.9 KB
    int t = threadIdx.x;
    int wid = t >> 6, lane = t & 63;
    int base = blockIdx.x * GN;

    // stage W2 (row-major [128][64]) transposed: thread t owns f=t&63, k-chunk (t>>6)*32
    {
        int f = t & 63, kc = (t >> 6) * 32;
        for (int k = kc; k < kc + 32; ++k)
            W2t[f * LDH + k] = W2[k * 64 + f];      // global read coalesced along f
    }
    // h1 tile: thread t owns node m=t>>3, k-range (t&7)*16..+16
    {
        int m = t >> 3, g = t & 7;
        int i = base + m;
        float2 xa = (i < n) ? xam[i] : make_float2(0.f, 0.f);
#pragma unroll
        for (int k = g * 16; k < g * 16 + 16; k += 4) {
            float4 wa = *reinterpret_cast<const float4*>(&W1[k]);        // W1[0][k..]
            float4 wb = *reinterpret_cast<const float4*>(&W1[128 + k]);  // W1[1][k..]
            float4 bb = *reinterpret_cast<const float4*>(&b1[k]);
            float4 h;
            h.x = fmaxf(fmaf(xa.y, wb.x, fmaf(xa.x, wa.x, bb.x)), 0.f);
            h.y = fmaxf(fmaf(xa.y, wb.y, fmaf(xa.x, wa.y, bb.y)), 0.f);
            h.z = fmaxf(fmaf(xa.y, wb.z, fmaf(xa.x, wa.z, bb.z)), 0.f);
            h.w = fmaxf(fmaf(xa.y, wb.w, fmaf(xa.x, wa.w, bb.w)), 0.f);
            *reinterpret_cast<float4*>(&h1s[m * LDH + k]) = h;
        }
    }
    __syncthreads();

    float acc[GM];
#pragma unroll
    for (int m = 0; m < GM; ++m) acc[m] = 0.f;
    int mbase = wid * GM;
#pragma unroll 2
    for (int k4 = 0; k4 < 32; ++k4) {             // NOT fully unrolled (round-5 lesson)
        float4 w = *reinterpret_cast<const float4*>(&W2t[lane * LDH + 4 * k4]);
#pragma unroll
        for (int m = 0; m < GM; ++m) {            // h reads are same-address broadcasts
            float4 h = *reinterpret_cast<const float4*>(&h1s[(mbase + m) * LDH + 4 * k4]);
            acc[m] = fmaf(h.x, w.x, acc[m]);
            acc[m] = fmaf(h.y, w.y, acc[m]);
            acc[m] = fmaf(h.z, w.z, acc[m]);
            acc[m] = fmaf(h.w, w.w, acc[m]);
        }
    }
#pragma unroll
    for (int m = 0; m < GM; ++m) {
        int i = base + mbase + m;
        if (i < n) m2[(size_t)i * 64 + lane] = acc[m] * dinv[i];  // pre-scaled by dinv[src]
    }
}

// ---------------- layer 2 gather + full epilogue, one wave per node ----------------
__global__ __launch_bounds__(256) void k_l2out(
    const float* __restrict__ m2, const float* __restrict__ dinv,
    const int* __restrict__ row_off, const int* __restrict__ csr_src,
    const float* __restrict__ b2, const float* __restrict__ Wp,
    const float* __restrict__ bp, float* __restrict__ out, int n) {
    int tid = threadIdx.x;
    int wid = tid >> 6, lane = tid & 63;
    float b2l = b2[lane], wpl = Wp[lane], bp0 = bp[0];
    int i = blockIdx.x * 4 + wid;
    if (i >= n) return;
    int r0 = row_off[i], r1 = row_off[i + 1];
    float acc = m2[(size_t)i * 64 + lane];          // self-loop term
    for (int j = r0; j < r1; ++j) {
        int s = csr_src[j];
        acc += m2[(size_t)s * 64 + lane];           // coalesced 256B row gather (L3-resident)
    }
    float v = fmaxf(acc * dinv[i] + b2l, 0.f) * wpl;
#pragma unroll
    for (int off = 32; off; off >>= 1) v += __shfl_xor(v, off);
    if (lane == 0) out[i] = 1.f / (1.f + expf(-(v + bp0)));
}

extern "C" void kernel_launch(void* const* d_in, const int* in_sizes, int n_in,
                              void* d_out, int out_size, void* d_ws, size_t ws_size,
                              hipStream_t stream) {
    const float* x  = (const float*)d_in[0];
    const int*   ei = (const int*)d_in[1];   // [2, E] int32
    const float* W1 = (const float*)d_in[2];
    const float* b1 = (const float*)d_in[3];
    const float* W2 = (const float*)d_in[4];
    const float* b2 = (const float*)d_in[5];
    const float* Wp = (const float*)d_in[6];
    const float* bp = (const float*)d_in[7];
    float* out = (float*)d_out;

    int n = in_sizes[0] / 2;
    int E = in_sizes[1] / 2;
    const int* src = ei;
    const int* dst = ei + E;

    char* ws = (char*)d_ws;
    size_t off = 0;
    auto alloc = [&](size_t bytes) -> void* {
        void* p = ws + off;
        off += (bytes + 255) & ~(size_t)255;
        return p;
    };
    int nb = (n + SCAN_EPB - 1) / SCAN_EPB;
    int*    deg     = (int*)alloc((size_t)n * 4);
    int*    bsum    = (int*)alloc((size_t)nb * 4);
    int*    row_off = (int*)alloc((size_t)(n + 1) * 4);
    int*    cursor  = (int*)alloc((size_t)n * 4);
    float*  dinv    = (float*)alloc((size_t)n * 4);
    float2* xsc     = (float2*)alloc((size_t)n * 8);
    float2* xam     = (float2*)alloc((size_t)n * 8);
    int*    csr_src = (int*)alloc((size_t)E * 4);
    float*  m2      = (float*)alloc((size_t)n * 64 * 4);
    (void)ws_size;

    hipMemsetAsync(deg, 0, (size_t)n * 4, stream);
    k_deg      <<<(E + 255) / 256, 256, 0, stream>>>(dst, deg, E);
    k_blocksum <<<nb, SCAN_TPB, 0, stream>>>(deg, bsum, n);
    k_scanbsum <<<1, 256, 0, stream>>>(bsum, row_off, nb, n);
    k_scanfinal<<<nb, SCAN_TPB, 0, stream>>>(deg, bsum, row_off, cursor, n);
    k_dinvx    <<<(n + 255) / 256, 256, 0, stream>>>(deg, x, dinv, xsc, n);
    k_fill     <<<(E + 255) / 256, 256, 0, stream>>>(src, dst, cursor, csr_src, E);
    k_agg1     <<<(n + 255) / 256, 256, 0, stream>>>(xsc, dinv, row_off, csr_src, xam, n);
    k_gemm1    <<<(n + GN - 1) / GN, 256, 0, stream>>>(xam, dinv, W1, b1, W2, m2, n);
    k_l2out    <<<(n + 3) / 4, 256, 0, stream>>>(m2, dinv, row_off, csr_src, b2, Wp, bp, out, n);
}

// Round 7
// 231.002 us; speedup vs baseline: 8.2500x; 1.0869x over previous
//
#include <hip/hip_runtime.h>
#include <math.h>

constexpr int SCAN_TPB = 256;
constexpr int SCAN_EPT = 8;                      // elements per thread
constexpr int SCAN_EPB = SCAN_TPB * SCAN_EPT;    // 2048 per block

// ---------------- degree (in-degree over dst) ----------------
__global__ void k_deg(const int* __restrict__ dst, int* __restrict__ deg, int E) {
    int i = blockIdx.x * blockDim.x + threadIdx.x;
    if (i < E) atomicAdd(&deg[dst[i]], 1);
}

// ---------------- scan phase A: per-block sums ----------------
__global__ __launch_bounds__(SCAN_TPB) void k_blocksum(const int* __restrict__ deg,
                                                       int* __restrict__ bsum, int n) {
    int t = threadIdx.x;
    int idx0 = blockIdx.x * SCAN_EPB + t * SCAN_EPT;
    int s = 0;
    if (idx0 + SCAN_EPT <= n) {
        const int4* p = reinterpret_cast<const int4*>(deg + idx0);
        int4 a = p[0], b = p[1];
        s = a.x + a.y + a.z + a.w + b.x + b.y + b.z + b.w;
    } else {
        for (int k = 0; k < SCAN_EPT; ++k) { int i = idx0 + k; if (i < n) s += deg[i]; }
    }
#pragma unroll
    for (int off = 32; off; off >>= 1) s += __shfl_xor(s, off);
    __shared__ int wsum[4];
    int lane = t & 63, wid = t >> 6;
    if (lane == 0) wsum[wid] = s;
    __syncthreads();
    if (t == 0) bsum[blockIdx.x] = wsum[0] + wsum[1] + wsum[2] + wsum[3];
}

// ---------------- scan phase B: exclusive-scan the block sums (tiny) ----------------
__global__ __launch_bounds__(256) void k_scanbsum(int* __restrict__ bsum,
                                                  int* __restrict__ row_off, int nb, int n) {
    int t = threadIdx.x, lane = t & 63, wid = t >> 6;
    __shared__ int wsum[4];
    int carry = 0;
    for (int base = 0; base < nb; base += 256) {
        int i = base + t;
        int v = (i < nb) ? bsum[i] : 0;
        int s = v;
#pragma unroll
        for (int off = 1; off < 64; off <<= 1) { int u = __shfl_up(s, off); if (lane >= off) s += u; }
        if (lane == 63) wsum[wid] = s;
        __syncthreads();
        int add = carry;
        for (int w = 0; w < wid; ++w) add += wsum[w];
        if (i < nb) bsum[i] = s - v + add;        // exclusive + carry
        carry += wsum[0] + wsum[1] + wsum[2] + wsum[3];
        __syncthreads();
    }
    if (t == 0) row_off[n] = carry;               // total edge count
}

// ---------------- scan phase C: final scan, write row_off + cursor ----------------
__global__ __launch_bounds__(SCAN_TPB) void k_scanfinal(const int* __restrict__ deg,
                                                        const int* __restrict__ bsum,
                                                        int* __restrict__ row_off,
                                                        int* __restrict__ cursor, int n) {
    int t = threadIdx.x, lane = t & 63, wid = t >> 6;
    int idx0 = blockIdx.x * SCAN_EPB + t * SCAN_EPT;
    int e[SCAN_EPT];
    bool full = (idx0 + SCAN_EPT <= n);
    if (full) {
        const int4* p = reinterpret_cast<const int4*>(deg + idx0);
        int4 a = p[0], b = p[1];
        e[0] = a.x; e[1] = a.y; e[2] = a.z; e[3] = a.w;
        e[4] = b.x; e[5] = b.y; e[6] = b.z; e[7] = b.w;
    } else {
        for (int k = 0; k < SCAN_EPT; ++k) { int i = idx0 + k; e[k] = (i < n) ? deg[i] : 0; }
    }
    int tsum = 0;
#pragma unroll
    for (int k = 0; k < SCAN_EPT; ++k) tsum += e[k];
    int s = tsum;
#pragma unroll
    for (int off = 1; off < 64; off <<= 1) { int u = __shfl_up(s, off); if (lane >= off) s += u; }
    __shared__ int wsum[4];
    if (lane == 63) wsum[wid] = s;
    __syncthreads();
    int add = bsum[blockIdx.x];
    for (int w = 0; w < wid; ++w) add += wsum[w];
    int run = s - tsum + add;                     // thread's exclusive prefix
    int o[SCAN_EPT];
#pragma unroll
    for (int k = 0; k < SCAN_EPT; ++k) { o[k] = run; run += e[k]; }
    if (full) {
        int4* ro = reinterpret_cast<int4*>(row_off + idx0);
        int4* cu = reinterpret_cast<int4*>(cursor + idx0);
        ro[0] = make_int4(o[0], o[1], o[2], o[3]);
        ro[1] = make_int4(o[4], o[5], o[6], o[7]);
        cu[0] = make_int4(o[0], o[1], o[2], o[3]);
        cu[1] = make_int4(o[4], o[5], o[6], o[7]);
    } else {
        for (int k = 0; k < SCAN_EPT; ++k) {
            int i = idx0 + k;
            if (i < n) { row_off[i] = o[k]; cursor[i] = o[k]; }
        }
    }
}

// ---------------- dinv + pre-scaled features xsc[i] = x[i]*dinv[i] ----------------
__global__ void k_dinvx(const int* __restrict__ deg, const float* __restrict__ x,
                        float* __restrict__ dinv, float2* __restrict__ xsc, int n) {
    int i = blockIdx.x * blockDim.x + threadIdx.x;
    if (i < n) {
        float di = rsqrtf((float)deg[i] + 1.0f);  // +1 self loop, always > 0
        dinv[i] = di;
        xsc[i] = make_float2(x[2 * i] * di, x[2 * i + 1] * di);
    }
}

// ---------------- CSR fill (counting sort by dst) ----------------
__global__ void k_fill(const int* __restrict__ src, const int* __restrict__ dst,
                       int* __restrict__ cursor, int* __restrict__ csr_src, int E) {
    int e = blockIdx.x * blockDim.x + threadIdx.x;
    if (e < E) {
        int pos = atomicAdd(&cursor[dst[e]], 1);
        csr_src[pos] = src[e];
    }
}

// ---------------- layer-1 sparse aggregation: xam[i] = dinv[i]*(xsc[i] + sum_nbr xsc[s])
__global__ __launch_bounds__(256) void k_agg1(
    const float2* __restrict__ xsc, const float* __restrict__ dinv,
    const int* __restrict__ row_off, const int* __restrict__ csr_src,
    float2* __restrict__ xam, int n) {
    int i = blockIdx.x * blockDim.x + threadIdx.x;
    if (i >= n) return;
    int r0 = row_off[i], r1 = row_off[i + 1];
    float2 self = xsc[i];
    float xa0 = self.x, xa1 = self.y;
    for (int j = r0; j < r1; ++j) {
        float2 v = xsc[csr_src[j]];               // 8B gather, xsc=1.6MB L2-resident
        xa0 += v.x; xa1 += v.y;
    }
    float di = dinv[i];
    xam[i] = make_float2(xa0 * di, xa1 * di);
}

// ---------------- layer-1 dense part: m2[i] = relu(xam[i]@W1+b1)@W2 * dinv[i]
// Round-6 lesson: the LDS-tiled version was DS-pipe-bound (9 DS : 32 FMA per
// k-quad, 8-way bank conflicts, 2 blocks/CU). New mapping: thread = node,
// feature = static register index. All weight reads are wave-uniform -> scalar
// loads (K$), ZERO LDS, zero syncthreads. h1 recomputed per k from 2 values.
__global__ __launch_bounds__(256) void k_gemm1(
    const float2* __restrict__ xam, const float* __restrict__ dinv,
    const float* __restrict__ W1, const float* __restrict__ b1,
    const float* __restrict__ W2, float* __restrict__ m2, int n) {
    int i = blockIdx.x * blockDim.x + threadIdx.x;
    if (i >= n) return;
    float2 xa = xam[i];
    float acc[64];
#pragma unroll
    for (int f = 0; f < 64; ++f) acc[f] = 0.f;
#pragma unroll 1
    for (int k = 0; k < 128; ++k) {               // unroll 1: one 64-SGPR W2 row live
        float h = fmaxf(fmaf(xa.y, W1[128 + k], fmaf(xa.x, W1[k], b1[k])), 0.f);
        const float* w2row = &W2[k * 64];         // wave-uniform -> s_load
#pragma unroll
        for (int f = 0; f < 64; ++f) acc[f] = fmaf(h, w2row[f], acc[f]);
    }
    float di = dinv[i];
    float4* mo = reinterpret_cast<float4*>(&m2[(size_t)i * 64]);
#pragma unroll
    for (int f4 = 0; f4 < 16; ++f4)
        mo[f4] = make_float4(acc[4 * f4] * di, acc[4 * f4 + 1] * di,
                             acc[4 * f4 + 2] * di, acc[4 * f4 + 3] * di);
}

// ---------------- layer 2 gather + full epilogue, one wave per node ----------------
__global__ __launch_bounds__(256) void k_l2out(
    const float* __restrict__ m2, const float* __restrict__ dinv,
    const int* __restrict__ row_off, const int* __restrict__ csr_src,
    const float* __restrict__ b2, const float* __restrict__ Wp,
    const float* __restrict__ bp, float* __restrict__ out, int n) {
    int tid = threadIdx.x;
    int wid = tid >> 6, lane = tid & 63;
    float b2l = b2[lane], wpl = Wp[lane], bp0 = bp[0];
    int i = blockIdx.x * 4 + wid;
    if (i >= n) return;
    int r0 = row_off[i], r1 = row_off[i + 1];
    float acc = m2[(size_t)i * 64 + lane];          // self-loop term
    for (int j = r0; j < r1; ++j) {
        int s = csr_src[j];
        acc += m2[(size_t)s * 64 + lane];           // coalesced 256B row gather (L3-resident)
    }
    float v = fmaxf(acc * dinv[i] + b2l, 0.f) * wpl;
#pragma unroll
    for (int off = 32; off; off >>= 1) v += __shfl_xor(v, off);
    if (lane == 0) out[i] = 1.f / (1.f + expf(-(v + bp0)));
}

extern "C" void kernel_launch(void* const* d_in, const int* in_sizes, int n_in,
                              void* d_out, int out_size, void* d_ws, size_t ws_size,
                              hipStream_t stream) {
    const float* x  = (const float*)d_in[0];
    const int*   ei = (const int*)d_in[1];   // [2, E] int32
    const float* W1 = (const float*)d_in[2];
    const float* b1 = (const float*)d_in[3];
    const float* W2 = (const float*)d_in[4];
    const float* b2 = (const float*)d_in[5];
    const float* Wp = (const float*)d_in[6];
    const float* bp = (const float*)d_in[7];
    float* out = (float*)d_out;

    int n = in_sizes[0] / 2;
    int E = in_sizes[1] / 2;
    const int* src = ei;
    const int* dst = ei + E;

    char* ws = (char*)d_ws;
    size_t off = 0;
    auto alloc = [&](size_t bytes) -> void* {
        void* p = ws + off;
        off += (bytes + 255) & ~(size_t)255;
        return p;
    };
    int nb = (n + SCAN_EPB - 1) / SCAN_EPB;
    int*    deg     = (int*)alloc((size_t)n * 4);
    int*    bsum    = (int*)alloc((size_t)nb * 4);
    int*    row_off = (int*)alloc((size_t)(n + 1) * 4);
    int*    cursor  = (int*)alloc((size_t)n * 4);
    float*  dinv    = (float*)alloc((size_t)n * 4);
    float2* xsc     = (float2*)alloc((size_t)n * 8);
    float2* xam     = (float2*)alloc((size_t)n * 8);
    int*    csr_src = (int*)alloc((size_t)E * 4);
    float*  m2      = (float*)alloc((size_t)n * 64 * 4);
    (void)ws_size;

    hipMemsetAsync(deg, 0, (size_t)n * 4, stream);
    k_deg      <<<(E + 255) / 256, 256, 0, stream>>>(dst, deg, E);
    k_blocksum <<<nb, SCAN_TPB, 0, stream>>>(deg, bsum, n);
    k_scanbsum <<<1, 256, 0, stream>>>(bsum, row_off, nb, n);
    k_scanfinal<<<nb, SCAN_TPB, 0, stream>>>(deg, bsum, row_off, cursor, n);
    k_dinvx    <<<(n + 255) / 256, 256, 0, stream>>>(deg, x, dinv, xsc, n);
    k_fill     <<<(E + 255) / 256, 256, 0, stream>>>(src, dst, cursor, csr_src, E);
    k_agg1     <<<(n + 255) / 256, 256, 0, stream>>>(xsc, dinv, row_off, csr_src, xam, n);
    k_gemm1    <<<(n + 255) / 256, 256, 0, stream>>>(xam, dinv, W1, b1, W2, m2, n);
    k_l2out    <<<(n + 3) / 4, 256, 0, stream>>>(m2, dinv, row_off, csr_src, b2, Wp, bp, out, n);
}

// Round 8
// 207.815 us; speedup vs baseline: 9.1705x; 1.1116x over previous
//
#include <hip/hip_runtime.h>
#include <math.h>

constexpr int SCAN_TPB = 256;
constexpr int SCAN_EPT = 8;                      // elements per thread
constexpr int SCAN_EPB = SCAN_TPB * SCAN_EPT;    // 2048 per block

// ---------------- degree (in-degree over dst) ----------------
__global__ void k_deg(const int* __restrict__ dst, int* __restrict__ deg, int E) {
    int i = blockIdx.x * blockDim.x + threadIdx.x;
    if (i < E) atomicAdd(&deg[dst[i]], 1);
}

// ---------------- scan phase A: per-block sums ----------------
__global__ __launch_bounds__(SCAN_TPB) void k_blocksum(const int* __restrict__ deg,
                                                       int* __restrict__ bsum, int n) {
    int t = threadIdx.x;
    int idx0 = blockIdx.x * SCAN_EPB + t * SCAN_EPT;
    int s = 0;
    if (idx0 + SCAN_EPT <= n) {
        const int4* p = reinterpret_cast<const int4*>(deg + idx0);
        int4 a = p[0], b = p[1];
        s = a.x + a.y + a.z + a.w + b.x + b.y + b.z + b.w;
    } else {
        for (int k = 0; k < SCAN_EPT; ++k) { int i = idx0 + k; if (i < n) s += deg[i]; }
    }
#pragma unroll
    for (int off = 32; off; off >>= 1) s += __shfl_xor(s, off);
    __shared__ int wsum[4];
    int lane = t & 63, wid = t >> 6;
    if (lane == 0) wsum[wid] = s;
    __syncthreads();
    if (t == 0) bsum[blockIdx.x] = wsum[0] + wsum[1] + wsum[2] + wsum[3];
}

// ---------------- scan phase B: exclusive-scan the block sums (tiny) ----------------
__global__ __launch_bounds__(256) void k_scanbsum(int* __restrict__ bsum,
                                                  int* __restrict__ row_off, int nb, int n) {
    int t = threadIdx.x, lane = t & 63, wid = t >> 6;
    __shared__ int wsum[4];
    int carry = 0;
    for (int base = 0; base < nb; base += 256) {
        int i = base + t;
        int v = (i < nb) ? bsum[i] : 0;
        int s = v;
#pragma unroll
        for (int off = 1; off < 64; off <<= 1) { int u = __shfl_up(s, off); if (lane >= off) s += u; }
        if (lane == 63) wsum[wid] = s;
        __syncthreads();
        int add = carry;
        for (int w = 0; w < wid; ++w) add += wsum[w];
        if (i < nb) bsum[i] = s - v + add;        // exclusive + carry
        carry += wsum[0] + wsum[1] + wsum[2] + wsum[3];
        __syncthreads();
    }
    if (t == 0) row_off[n] = carry;               // total edge count
}

// ---------------- scan phase C: final scan, write row_off + cursor ----------------
__global__ __launch_bounds__(SCAN_TPB) void k_scanfinal(const int* __restrict__ deg,
                                                        const int* __restrict__ bsum,
                                                        int* __restrict__ row_off,
                                                        int* __restrict__ cursor, int n) {
    int t = threadIdx.x, lane = t & 63, wid = t >> 6;
    int idx0 = blockIdx.x * SCAN_EPB + t * SCAN_EPT;
    int e[SCAN_EPT];
    bool full = (idx0 + SCAN_EPT <= n);
    if (full) {
        const int4* p = reinterpret_cast<const int4*>(deg + idx0);
        int4 a = p[0], b = p[1];
        e[0] = a.x; e[1] = a.y; e[2] = a.z; e[3] = a.w;
        e[4] = b.x; e[5] = b.y; e[6] = b.z; e[7] = b.w;
    } else {
        for (int k = 0; k < SCAN_EPT; ++k) { int i = idx0 + k; e[k] = (i < n) ? deg[i] : 0; }
    }
    int tsum = 0;
#pragma unroll
    for (int k = 0; k < SCAN_EPT; ++k) tsum += e[k];
    int s = tsum;
#pragma unroll
    for (int off = 1; off < 64; off <<= 1) { int u = __shfl_up(s, off); if (lane >= off) s += u; }
    __shared__ int wsum[4];
    if (lane == 63) wsum[wid] = s;
    __syncthreads();
    int add = bsum[blockIdx.x];
    for (int w = 0; w < wid; ++w) add += wsum[w];
    int run = s - tsum + add;                     // thread's exclusive prefix
    int o[SCAN_EPT];
#pragma unroll
    for (int k = 0; k < SCAN_EPT; ++k) { o[k] = run; run += e[k]; }
    if (full) {
        int4* ro = reinterpret_cast<int4*>(row_off + idx0);
        int4* cu = reinterpret_cast<int4*>(cursor + idx0);
        ro[0] = make_int4(o[0], o[1], o[2], o[3]);
        ro[1] = make_int4(o[4], o[5], o[6], o[7]);
        cu[0] = make_int4(o[0], o[1], o[2], o[3]);
        cu[1] = make_int4(o[4], o[5], o[6], o[7]);
    } else {
        for (int k = 0; k < SCAN_EPT; ++k) {
            int i = idx0 + k;
            if (i < n) { row_off[i] = o[k]; cursor[i] = o[k]; }
        }
    }
}

// ---------------- dinv + pre-scaled features xsc[i] = x[i]*dinv[i] ----------------
__global__ void k_dinvx(const int* __restrict__ deg, const float* __restrict__ x,
                        float* __restrict__ dinv, float2* __restrict__ xsc, int n) {
    int i = blockIdx.x * blockDim.x + threadIdx.x;
    if (i < n) {
        float di = rsqrtf((float)deg[i] + 1.0f);  // +1 self loop, always > 0
        dinv[i] = di;
        xsc[i] = make_float2(x[2 * i] * di, x[2 * i + 1] * di);
    }
}

// ---------------- CSR fill (counting sort by dst) ----------------
__global__ void k_fill(const int* __restrict__ src, const int* __restrict__ dst,
                       int* __restrict__ cursor, int* __restrict__ csr_src, int E) {
    int e = blockIdx.x * blockDim.x + threadIdx.x;
    if (e < E) {
        int pos = atomicAdd(&cursor[dst[e]], 1);
        csr_src[pos] = src[e];
    }
}

// ---------------- layer-1 sparse aggregation: xam[i] = dinv[i]*(xsc[i] + sum_nbr xsc[s])
__global__ __launch_bounds__(256) void k_agg1(
    const float2* __restrict__ xsc, const float* __restrict__ dinv,
    const int* __restrict__ row_off, const int* __restrict__ csr_src,
    float2* __restrict__ xam, int n) {
    int i = blockIdx.x * blockDim.x + threadIdx.x;
    if (i >= n) return;
    int r0 = row_off[i], r1 = row_off[i + 1];
    float2 self = xsc[i];
    float xa0 = self.x, xa1 = self.y;
    for (int j = r0; j < r1; ++j) {
        float2 v = xsc[csr_src[j]];               // 8B gather, xsc=1.6MB L2-resident
        xa0 += v.x; xa1 += v.y;
    }
    float di = dinv[i];
    xam[i] = make_float2(xa0 * di, xa1 * di);
}

// ---------------- layer-1 dense part: m2[i] = relu(xam[i]@W1+b1)@W2 * dinv[i]
// thread = node, feature = static register index; weight reads wave-uniform ->
// scalar loads, zero LDS (round-6 lesson). unroll 1 keeps one W2 row in SGPRs.
__global__ __launch_bounds__(256) void k_gemm1(
    const float2* __restrict__ xam, const float* __restrict__ dinv,
    const float* __restrict__ W1, const float* __restrict__ b1,
    const float* __restrict__ W2, float* __restrict__ m2, int n) {
    int i = blockIdx.x * blockDim.x + threadIdx.x;
    if (i >= n) return;
    float2 xa = xam[i];
    float acc[64];
#pragma unroll
    for (int f = 0; f < 64; ++f) acc[f] = 0.f;
#pragma unroll 1
    for (int k = 0; k < 128; ++k) {               // unroll 1: one 64-SGPR W2 row live
        float h = fmaxf(fmaf(xa.y, W1[128 + k], fmaf(xa.x, W1[k], b1[k])), 0.f);
        const float* w2row = &W2[k * 64];         // wave-uniform -> s_load
#pragma unroll
        for (int f = 0; f < 64; ++f) acc[f] = fmaf(h, w2row[f], acc[f]);
    }
    float di = dinv[i];
    float4* mo = reinterpret_cast<float4*>(&m2[(size_t)i * 64]);
#pragma unroll
    for (int f4 = 0; f4 < 16; ++f4)
        mo[f4] = make_float4(acc[4 * f4] * di, acc[4 * f4 + 1] * di,
                             acc[4 * f4 + 2] * di, acc[4 * f4 + 3] * di);
}

// ---------------- layer 2 gather + full epilogue, one wave per node ----------------
// Round-7 lesson: serial per-edge gather chain (index -> row -> acc) left one
// 256B gather in flight per wave -> latency-bound at 90 µs. Remap lane =
// (edge_slot[0..3], f4[0..15]): 4 edge rows in flight per iteration (1KB/wave
// instr), avg-deg-3 node completes in ONE iteration. Self-loop = edge 0.
__global__ __launch_bounds__(256) void k_l2out(
    const float4* __restrict__ m2, const float* __restrict__ dinv,
    const int* __restrict__ row_off, const int* __restrict__ csr_src,
    const float* __restrict__ b2, const float* __restrict__ Wp,
    const float* __restrict__ bp, float* __restrict__ out, int n) {
    int tid = threadIdx.x;
    int wid = tid >> 6, lane = tid & 63;
    int es = lane >> 4;                            // edge slot 0..3
    int f4 = lane & 15;                            // feature quad 0..15
    int i = blockIdx.x * 4 + wid;
    if (i >= n) return;
    int r0 = row_off[i], r1 = row_off[i + 1];
    int cnt = r1 - r0 + 1;                         // neighbors + self
    float4 acc = make_float4(0.f, 0.f, 0.f, 0.f);
    for (int e = es; e < cnt; e += 4) {            // 4 edges in flight across slots
        int s = (e == 0) ? i : csr_src[r0 + e - 1];
        float4 v = m2[(size_t)s * 16 + f4];        // 4 rows/iter, 1KB per wave instr
        acc.x += v.x; acc.y += v.y; acc.z += v.z; acc.w += v.w;
    }
    // sum the 4 edge slots (lanes {f4, f4+16, f4+32, f4+48})
#pragma unroll
    for (int off = 16; off >= 16; off >>= 1) { }   // (clarity: two explicit swaps below)
    acc.x += __shfl_xor(acc.x, 16); acc.y += __shfl_xor(acc.y, 16);
    acc.z += __shfl_xor(acc.z, 16); acc.w += __shfl_xor(acc.w, 16);
    acc.x += __shfl_xor(acc.x, 32); acc.y += __shfl_xor(acc.y, 32);
    acc.z += __shfl_xor(acc.z, 32); acc.w += __shfl_xor(acc.w, 32);
    // epilogue: 4 features per lane (replicated across edge slots, harmless)
    float di = dinv[i];
    float4 b2v = reinterpret_cast<const float4*>(b2)[f4];
    float4 wpv = reinterpret_cast<const float4*>(Wp)[f4];
    float v = fmaxf(fmaf(acc.x, di, b2v.x), 0.f) * wpv.x
            + fmaxf(fmaf(acc.y, di, b2v.y), 0.f) * wpv.y
            + fmaxf(fmaf(acc.z, di, b2v.z), 0.f) * wpv.z
            + fmaxf(fmaf(acc.w, di, b2v.w), 0.f) * wpv.w;
#pragma unroll
    for (int off = 8; off; off >>= 1) v += __shfl_xor(v, off);  // reduce 16 f4 groups
    if (lane == 0) out[i] = 1.f / (1.f + expf(-(v + bp[0])));
}

extern "C" void kernel_launch(void* const* d_in, const int* in_sizes, int n_in,
                              void* d_out, int out_size, void* d_ws, size_t ws_size,
                              hipStream_t stream) {
    const float* x  = (const float*)d_in[0];
    const int*   ei = (const int*)d_in[1];   // [2, E] int32
    const float* W1 = (const float*)d_in[2];
    const float* b1 = (const float*)d_in[3];
    const float* W2 = (const float*)d_in[4];
    const float* b2 = (const float*)d_in[5];
    const float* Wp = (const float*)d_in[6];
    const float* bp = (const float*)d_in[7];
    float* out = (float*)d_out;

    int n = in_sizes[0] / 2;
    int E = in_sizes[1] / 2;
    const int* src = ei;
    const int* dst = ei + E;

    char* ws = (char*)d_ws;
    size_t off = 0;
    auto alloc = [&](size_t bytes) -> void* {
        void* p = ws + off;
        off += (bytes + 255) & ~(size_t)255;
        return p;
    };
    int nb = (n + SCAN_EPB - 1) / SCAN_EPB;
    int*    deg     = (int*)alloc((size_t)n * 4);
    int*    bsum    = (int*)alloc((size_t)nb * 4);
    int*    row_off = (int*)alloc((size_t)(n + 1) * 4);
    int*    cursor  = (int*)alloc((size_t)n * 4);
    float*  dinv    = (float*)alloc((size_t)n * 4);
    float2* xsc     = (float2*)alloc((size_t)n * 8);
    float2* xam     = (float2*)alloc((size_t)n * 8);
    int*    csr_src = (int*)alloc((size_t)E * 4);
    float*  m2      = (float*)alloc((size_t)n * 64 * 4);
    (void)ws_size;

    hipMemsetAsync(deg, 0, (size_t)n * 4, stream);
    k_deg      <<<(E + 255) / 256, 256, 0, stream>>>(dst, deg, E);
    k_blocksum <<<nb, SCAN_TPB, 0, stream>>>(deg, bsum, n);
    k_scanbsum <<<1, 256, 0, stream>>>(bsum, row_off, nb, n);
    k_scanfinal<<<nb, SCAN_TPB, 0, stream>>>(deg, bsum, row_off, cursor, n);
    k_dinvx    <<<(n + 255) / 256, 256, 0, stream>>>(deg, x, dinv, xsc, n);
    k_fill     <<<(E + 255) / 256, 256, 0, stream>>>(src, dst, cursor, csr_src, E);
    k_agg1     <<<(n + 255) / 256, 256, 0, stream>>>(xsc, dinv, row_off, csr_src, xam, n);
    k_gemm1    <<<(n + 255) / 256, 256, 0, stream>>>(xam, dinv, W1, b1, W2, m2, n);
    k_l2out    <<<(n + 3) / 4, 256, 0, stream>>>((const float4*)m2, dinv, row_off, csr_src,
                                                 b2, Wp, bp, out, n);
}

// Round 9
// 202.269 us; speedup vs baseline: 9.4219x; 1.0274x over previous
//
#include <hip/hip_runtime.h>
#include <math.h>

constexpr int SCAN_TPB = 256;
constexpr int SCAN_EPT = 8;                      // elements per thread
constexpr int SCAN_EPB = SCAN_TPB * SCAN_EPT;    // 2048 per block

// ---------------- degree (in-degree over dst) ----------------
__global__ void k_deg(const int* __restrict__ dst, int* __restrict__ deg, int E) {
    int i = blockIdx.x * blockDim.x + threadIdx.x;
    if (i < E) atomicAdd(&deg[dst[i]], 1);
}

// ---------------- scan phase A: per-block sums ----------------
__global__ __launch_bounds__(SCAN_TPB) void k_blocksum(const int* __restrict__ deg,
                                                       int* __restrict__ bsum, int n) {
    int t = threadIdx.x;
    int idx0 = blockIdx.x * SCAN_EPB + t * SCAN_EPT;
    int s = 0;
    if (idx0 + SCAN_EPT <= n) {
        const int4* p = reinterpret_cast<const int4*>(deg + idx0);
        int4 a = p[0], b = p[1];
        s = a.x + a.y + a.z + a.w + b.x + b.y + b.z + b.w;
    } else {
        for (int k = 0; k < SCAN_EPT; ++k) { int i = idx0 + k; if (i < n) s += deg[i]; }
    }
#pragma unroll
    for (int off = 32; off; off >>= 1) s += __shfl_xor(s, off);
    __shared__ int wsum[4];
    int lane = t & 63, wid = t >> 6;
    if (lane == 0) wsum[wid] = s;
    __syncthreads();
    if (t == 0) bsum[blockIdx.x] = wsum[0] + wsum[1] + wsum[2] + wsum[3];
}

// ---------------- scan phase B: exclusive-scan the block sums (tiny) ----------------
__global__ __launch_bounds__(256) void k_scanbsum(int* __restrict__ bsum,
                                                  int* __restrict__ row_off, int nb, int n) {
    int t = threadIdx.x, lane = t & 63, wid = t >> 6;
    __shared__ int wsum[4];
    int carry = 0;
    for (int base = 0; base < nb; base += 256) {
        int i = base + t;
        int v = (i < nb) ? bsum[i] : 0;
        int s = v;
#pragma unroll
        for (int off = 1; off < 64; off <<= 1) { int u = __shfl_up(s, off); if (lane >= off) s += u; }
        if (lane == 63) wsum[wid] = s;
        __syncthreads();
        int add = carry;
        for (int w = 0; w < wid; ++w) add += wsum[w];
        if (i < nb) bsum[i] = s - v + add;        // exclusive + carry
        carry += wsum[0] + wsum[1] + wsum[2] + wsum[3];
        __syncthreads();
    }
    if (t == 0) row_off[n] = carry;               // total edge count
}

// ---------------- scan phase C: final scan, write row_off + cursor ----------------
__global__ __launch_bounds__(SCAN_TPB) void k_scanfinal(const int* __restrict__ deg,
                                                        const int* __restrict__ bsum,
                                                        int* __restrict__ row_off,
                                                        int* __restrict__ cursor, int n) {
    int t = threadIdx.x, lane = t & 63, wid = t >> 6;
    int idx0 = blockIdx.x * SCAN_EPB + t * SCAN_EPT;
    int e[SCAN_EPT];
    bool full = (idx0 + SCAN_EPT <= n);
    if (full) {
        const int4* p = reinterpret_cast<const int4*>(deg + idx0);
        int4 a = p[0], b = p[1];
        e[0] = a.x; e[1] = a.y; e[2] = a.z; e[3] = a.w;
        e[4] = b.x; e[5] = b.y; e[6] = b.z; e[7] = b.w;
    } else {
        for (int k = 0; k < SCAN_EPT; ++k) { int i = idx0 + k; e[k] = (i < n) ? deg[i] : 0; }
    }
    int tsum = 0;
#pragma unroll
    for (int k = 0; k < SCAN_EPT; ++k) tsum += e[k];
    int s = tsum;
#pragma unroll
    for (int off = 1; off < 64; off <<= 1) { int u = __shfl_up(s, off); if (lane >= off) s += u; }
    __shared__ int wsum[4];
    if (lane == 63) wsum[wid] = s;
    __syncthreads();
    int add = bsum[blockIdx.x];
    for (int w = 0; w < wid; ++w) add += wsum[w];
    int run = s - tsum + add;                     // thread's exclusive prefix
    int o[SCAN_EPT];
#pragma unroll
    for (int k = 0; k < SCAN_EPT; ++k) { o[k] = run; run += e[k]; }
    if (full) {
        int4* ro = reinterpret_cast<int4*>(row_off + idx0);
        int4* cu = reinterpret_cast<int4*>(cursor + idx0);
        ro[0] = make_int4(o[0], o[1], o[2], o[3]);
        ro[1] = make_int4(o[4], o[5], o[6], o[7]);
        cu[0] = make_int4(o[0], o[1], o[2], o[3]);
        cu[1] = make_int4(o[4], o[5], o[6], o[7]);
    } else {
        for (int k = 0; k < SCAN_EPT; ++k) {
            int i = idx0 + k;
            if (i < n) { row_off[i] = o[k]; cursor[i] = o[k]; }
        }
    }
}

// ---------------- dinv + pre-scaled features xsc[i] = x[i]*dinv[i] ----------------
__global__ void k_dinvx(const int* __restrict__ deg, const float* __restrict__ x,
                        float* __restrict__ dinv, float2* __restrict__ xsc, int n) {
    int i = blockIdx.x * blockDim.x + threadIdx.x;
    if (i < n) {
        float di = rsqrtf((float)deg[i] + 1.0f);  // +1 self loop, always > 0
        dinv[i] = di;
        xsc[i] = make_float2(x[2 * i] * di, x[2 * i + 1] * di);
    }
}

// ---------------- CSR fill (counting sort by dst) ----------------
__global__ void k_fill(const int* __restrict__ src, const int* __restrict__ dst,
                       int* __restrict__ cursor, int* __restrict__ csr_src, int E) {
    int e = blockIdx.x * blockDim.x + threadIdx.x;
    if (e < E) {
        int pos = atomicAdd(&cursor[dst[e]], 1);
        csr_src[pos] = src[e];
    }
}

// ---------------- layer-1 sparse aggregation: xam[i] = dinv[i]*(xsc[i] + sum_nbr xsc[s])
__global__ __launch_bounds__(256) void k_agg1(
    const float2* __restrict__ xsc, const float* __restrict__ dinv,
    const int* __restrict__ row_off, const int* __restrict__ csr_src,
    float2* __restrict__ xam, int n) {
    int i = blockIdx.x * blockDim.x + threadIdx.x;
    if (i >= n) return;
    int r0 = row_off[i], r1 = row_off[i + 1];
    float2 self = xsc[i];
    float xa0 = self.x, xa1 = self.y;
    for (int j = r0; j < r1; ++j) {
        float2 v = xsc[csr_src[j]];               // 8B gather, xsc=1.6MB L2-resident
        xa0 += v.x; xa1 += v.y;
    }
    float di = dinv[i];
    xam[i] = make_float2(xa0 * di, xa1 * di);
}

// ---------------- layer-1 dense part: m2[i] = relu(xam[i]@W1+b1)@W2 * dinv[i]
// Round-8 lesson: acc[64] exceeded the compiler's occupancy-targeted register
// budget, so it strip-mined f into ~4 passes (VGPR=40, k-loop 4x, s_load stalls
// at 3 waves/SIMD -> VALUBusy 30%). Fix: split f across wave pairs. fh=tid>>7
// is wave-uniform but unprovable -> readfirstlane keeps w2row on the s_load
// path. acc[32]+misc ~48 VGPR fits the 8-wave budget; grid doubles to 24 w/CU.
__global__ __launch_bounds__(256, 4) void k_gemm1(
    const float2* __restrict__ xam, const float* __restrict__ dinv,
    const float* __restrict__ W1, const float* __restrict__ b1,
    const float* __restrict__ W2, float* __restrict__ m2, int n) {
    int t = threadIdx.x;
    int fh = __builtin_amdgcn_readfirstlane(t >> 7);   // 0/1, wave-uniform -> SGPR
    int i = blockIdx.x * 128 + (t & 127);
    if (i >= n) return;
    float2 xa = xam[i];
    float acc[32];
#pragma unroll
    for (int f = 0; f < 32; ++f) acc[f] = 0.f;
    const float* W2h = W2 + fh * 32;              // this wave's 32-feature half
#pragma unroll 1
    for (int k = 0; k < 128; ++k) {               // unroll 1: one 32-SGPR row live
        float h = fmaxf(fmaf(xa.y, W1[128 + k], fmaf(xa.x, W1[k], b1[k])), 0.f);
        const float* w2row = &W2h[k * 64];        // wave-uniform -> s_load
#pragma unroll
        for (int f = 0; f < 32; ++f) acc[f] = fmaf(h, w2row[f], acc[f]);
    }
    float di = dinv[i];
    float4* mo = reinterpret_cast<float4*>(&m2[(size_t)i * 64 + fh * 32]);
#pragma unroll
    for (int f4 = 0; f4 < 8; ++f4)
        mo[f4] = make_float4(acc[4 * f4] * di, acc[4 * f4 + 1] * di,
                             acc[4 * f4 + 2] * di, acc[4 * f4 + 3] * di);
}

// ---------------- layer 2 gather + full epilogue, one wave per node ----------------
// lane = (edge_slot[0..3], f4[0..15]): 4 edge rows in flight per iteration,
// avg-deg-3 node completes its gather in ONE iteration. Self-loop = edge 0.
__global__ __launch_bounds__(256) void k_l2out(
    const float4* __restrict__ m2, const float* __restrict__ dinv,
    const int* __restrict__ row_off, const int* __restrict__ csr_src,
    const float* __restrict__ b2, const float* __restrict__ Wp,
    const float* __restrict__ bp, float* __restrict__ out, int n) {
    int tid = threadIdx.x;
    int wid = tid >> 6, lane = tid & 63;
    int es = lane >> 4;                            // edge slot 0..3
    int f4 = lane & 15;                            // feature quad 0..15
    int i = blockIdx.x * 4 + wid;
    if (i >= n) return;
    int r0 = row_off[i], r1 = row_off[i + 1];
    int cnt = r1 - r0 + 1;                         // neighbors + self
    float4 acc = make_float4(0.f, 0.f, 0.f, 0.f);
    for (int e = es; e < cnt; e += 4) {            // 4 edges in flight across slots
        int s = (e == 0) ? i : csr_src[r0 + e - 1];
        float4 v = m2[(size_t)s * 16 + f4];        // 4 rows/iter, 1KB per wave instr
        acc.x += v.x; acc.y += v.y; acc.z += v.z; acc.w += v.w;
    }
    acc.x += __shfl_xor(acc.x, 16); acc.y += __shfl_xor(acc.y, 16);
    acc.z += __shfl_xor(acc.z, 16); acc.w += __shfl_xor(acc.w, 16);
    acc.x += __shfl_xor(acc.x, 32); acc.y += __shfl_xor(acc.y, 32);
    acc.z += __shfl_xor(acc.z, 32); acc.w += __shfl_xor(acc.w, 32);
    float di = dinv[i];
    float4 b2v = reinterpret_cast<const float4*>(b2)[f4];
    float4 wpv = reinterpret_cast<const float4*>(Wp)[f4];
    float v = fmaxf(fmaf(acc.x, di, b2v.x), 0.f) * wpv.x
            + fmaxf(fmaf(acc.y, di, b2v.y), 0.f) * wpv.y
            + fmaxf(fmaf(acc.z, di, b2v.z), 0.f) * wpv.z
            + fmaxf(fmaf(acc.w, di, b2v.w), 0.f) * wpv.w;
#pragma unroll
    for (int off = 8; off; off >>= 1) v += __shfl_xor(v, off);  // reduce 16 f4 groups
    if (lane == 0) out[i] = 1.f / (1.f + expf(-(v + bp[0])));
}

extern "C" void kernel_launch(void* const* d_in, const int* in_sizes, int n_in,
                              void* d_out, int out_size, void* d_ws, size_t ws_size,
                              hipStream_t stream) {
    const float* x  = (const float*)d_in[0];
    const int*   ei = (const int*)d_in[1];   // [2, E] int32
    const float* W1 = (const float*)d_in[2];
    const float* b1 = (const float*)d_in[3];
    const float* W2 = (const float*)d_in[4];
    const float* b2 = (const float*)d_in[5];
    const float* Wp = (const float*)d_in[6];
    const float* bp = (const float*)d_in[7];
    float* out = (float*)d_out;

    int n = in_sizes[0] / 2;
    int E = in_sizes[1] / 2;
    const int* src = ei;
    const int* dst = ei + E;

    char* ws = (char*)d_ws;
    size_t off = 0;
    auto alloc = [&](size_t bytes) -> void* {
        void* p = ws + off;
        off += (bytes + 255) & ~(size_t)255;
        return p;
    };
    int nb = (n + SCAN_EPB - 1) / SCAN_EPB;
    int*    deg     = (int*)alloc((size_t)n * 4);
    int*    bsum    = (int*)alloc((size_t)nb * 4);
    int*    row_off = (int*)alloc((size_t)(n + 1) * 4);
    int*    cursor  = (int*)alloc((size_t)n * 4);
    float*  dinv    = (float*)alloc((size_t)n * 4);
    float2* xsc     = (float2*)alloc((size_t)n * 8);
    float2* xam     = (float2*)alloc((size_t)n * 8);
    int*    csr_src = (int*)alloc((size_t)E * 4);
    float*  m2      = (float*)alloc((size_t)n * 64 * 4);
    (void)ws_size;

    hipMemsetAsync(deg, 0, (size_t)n * 4, stream);
    k_deg      <<<(E + 255) / 256, 256, 0, stream>>>(dst, deg, E);
    k_blocksum <<<nb, SCAN_TPB, 0, stream>>>(deg, bsum, n);
    k_scanbsum <<<1, 256, 0, stream>>>(bsum, row_off, nb, n);
    k_scanfinal<<<nb, SCAN_TPB, 0, stream>>>(deg, bsum, row_off, cursor, n);
    k_dinvx    <<<(n + 255) / 256, 256, 0, stream>>>(deg, x, dinv, xsc, n);
    k_fill     <<<(E + 255) / 256, 256, 0, stream>>>(src, dst, cursor, csr_src, E);
    k_agg1     <<<(n + 255) / 256, 256, 0, stream>>>(xsc, dinv, row_off, csr_src, xam, n);
    k_gemm1    <<<(n + 127) / 128, 256, 0, stream>>>(xam, dinv, W1, b1, W2, m2, n);
    k_l2out    <<<(n + 3) / 4, 256, 0, stream>>>((const float4*)m2, dinv, row_off, csr_src,
                                                 b2, Wp, bp, out, n);
}